// Round 7
// baseline (37.742 us; speedup 1.0000x reference)
//
#include <hip/hip_runtime.h>
#include <math.h>

#define D_IN 768
#define NLAB 28

// ================= bit-location maps per epoch =================
struct Map { int rb[2]; int lb[6]; int wb[4]; };
constexpr Map MP[4] = {
    {{10, 11}, {4, 5, 6, 7, 8, 9}, {0, 1, 2, 3}},
    {{0, 1}, {2, 3, 8, 9, 10, 11}, {4, 5, 6, 7}},
    {{6, 7}, {5, 4, 2, 3, 0, 1}, {8, 9, 10, 11}},   // lb permuted: hot bits 5,4 on DPP lanes
    {{0, 1}, {2, 3, 8, 9, 10, 11}, {4, 5, 6, 7}},
};
constexpr int regPos(int e, int b) { for (int k = 0; k < 2; ++k) if (MP[e].rb[k] == b) return k; return -1; }
constexpr int lanePos(int e, int b) { for (int j = 0; j < 6; ++j) if (MP[e].lb[j] == b) return j; return -1; }
constexpr int wavePos(int e, int b) { for (int m = 0; m < 4; ++m) if (MP[e].wb[m] == b) return m; return -1; }

constexpr int stateOf(int e, int wv, int lane, int r) {
    int i = 0;
    for (int k = 0; k < 2; ++k) i |= ((r >> k) & 1) << MP[e].rb[k];
    for (int j = 0; j < 6; ++j) i |= ((lane >> j) & 1) << MP[e].lb[j];
    for (int m = 0; m < 4; ++m) i |= ((wv >> m) & 1) << MP[e].wb[m];
    return i;
}
constexpr int slotOf(int e, int i) {
    int r = 0, ln = 0, wv = 0;
    for (int k = 0; k < 2; ++k) r |= ((i >> MP[e].rb[k]) & 1) << k;
    for (int j = 0; j < 6; ++j) ln |= ((i >> MP[e].lb[j]) & 1) << j;
    for (int m = 0; m < 4; ++m) wv |= ((i >> MP[e].wb[m]) & 1) << m;
    return (wv << 8) | (ln << 2) | r;
}
constexpr int swzl(int s) { return s ^ (((s >> 4) ^ (s >> 8)) & 15); }  // GF(2)-linear

// ================= cross-lane exchange at distance 2^J =================
template <int J>
__device__ __forceinline__ float lx(float v) {
    if constexpr (J == 0 || J == 1 || J == 3) {
        constexpr int ctrl = (J == 0) ? 0xB1 : (J == 1) ? 0x4E : 0x128;
        return __int_as_float(__builtin_amdgcn_update_dpp(
            0, __float_as_int(v), ctrl, 0xF, 0xF, true));
    } else if constexpr (J == 2 || J == 4) {
        constexpr int off = (J == 2) ? 0x101F : 0x401F;  // ds_swizzle xor4 / xor16
        return __int_as_float(__builtin_amdgcn_ds_swizzle(__float_as_int(v), off));
    } else {
        return __shfl_xor(v, 32, 64);
    }
}
__device__ __forceinline__ float waveRed(float v) {
    v += lx<0>(v); v += lx<1>(v); v += lx<2>(v);
    v += lx<3>(v); v += lx<4>(v); v += lx<5>(v);
    return v;
}

// ======= packed-f32 complex helpers: u stored as rr=(ur,ur), im=(-ui,ui) =======
struct CU2 { float2 rr, im; };
struct G4 { CU2 u00, u01, u10, u11; };  // 64 B per gate

// uniform (SGPR) operand versions — gate data lives in SGPRs via s_load
__device__ __forceinline__ float2 cmuls(const CU2 u, const float2 a) {
    float2 t;
    asm("v_pk_mul_f32 %0, %1, %2 op_sel:[0,1] op_sel_hi:[1,0]"
        : "=v"(t) : "s"(u.im), "v"(a));
    asm("v_pk_fma_f32 %0, %1, %2, %3"
        : "=v"(t) : "s"(u.rr), "v"(a), "v"(t));
    return t;
}
__device__ __forceinline__ float2 cfmas(const CU2 u, const float2 a, float2 acc) {
    asm("v_pk_fma_f32 %0, %1, %2, %3 op_sel:[0,1,0] op_sel_hi:[1,0,1]"
        : "=v"(acc) : "s"(u.im), "v"(a), "v"(acc));
    asm("v_pk_fma_f32 %0, %1, %2, %3"
        : "=v"(acc) : "s"(u.rr), "v"(a), "v"(acc));
    return acc;
}
// divergent (VGPR) operand versions — for lane-selected coefficients
__device__ __forceinline__ float2 cmulv(const CU2 u, const float2 a) {
    float2 t;
    asm("v_pk_mul_f32 %0, %1, %2 op_sel:[0,1] op_sel_hi:[1,0]"
        : "=v"(t) : "v"(u.im), "v"(a));
    asm("v_pk_fma_f32 %0, %1, %2, %3"
        : "=v"(t) : "v"(u.rr), "v"(a), "v"(t));
    return t;
}
__device__ __forceinline__ float2 cfmav(const CU2 u, const float2 a, float2 acc) {
    asm("v_pk_fma_f32 %0, %1, %2, %3 op_sel:[0,1,0] op_sel_hi:[1,0,1]"
        : "=v"(acc) : "v"(u.im), "v"(a), "v"(acc));
    asm("v_pk_fma_f32 %0, %1, %2, %3"
        : "=v"(acc) : "v"(u.rr), "v"(a), "v"(acc));
    return acc;
}

// ================= gates =================
template <int E, int B>
__device__ __forceinline__ void rotg(float2 (&a)[4], int lane, const G4* __restrict__ gp) {
    const G4 g = *gp;  // uniform address -> s_load_dwordx16 into SGPRs
    constexpr int k = regPos(E, B);
    if constexpr (k >= 0) {
        constexpr int m = 1 << k;
#pragma unroll
        for (int r = 0; r < 4; ++r)
            if (!(r & m)) {
                const float2 a0 = a[r], a1 = a[r | m];
                a[r]     = cfmas(g.u01, a1, cmuls(g.u00, a0));
                a[r | m] = cfmas(g.u10, a0, cmuls(g.u11, a1));
            }
    } else {
        constexpr int j = lanePos(E, B);
        static_assert(j >= 0, "rot on wave bit");
        const bool hi = (lane >> j) & 1;
        CU2 co, cp;
        co.rr = hi ? g.u11.rr : g.u00.rr;  co.im = hi ? g.u11.im : g.u00.im;
        cp.rr = hi ? g.u10.rr : g.u01.rr;  cp.im = hi ? g.u10.im : g.u01.im;
#pragma unroll
        for (int r = 0; r < 4; ++r) {
            float2 p;
            p.x = lx<j>(a[r].x);
            p.y = lx<j>(a[r].y);
            a[r] = cfmav(cp, p, cmulv(co, a[r]));
        }
    }
}

template <int E, int C, int T>
__device__ __forceinline__ void cnot(float2 (&a)[4], int lane, int wv) {
    constexpr int kc = regPos(E, C), jc = lanePos(E, C), mc = wavePos(E, C);
    constexpr int kt = regPos(E, T), jt = lanePos(E, T);
    static_assert(wavePos(E, T) < 0, "cnot target on wave bit");
    if constexpr (kt >= 0) {
        constexpr int mt = 1 << kt;
        if constexpr (kc >= 0) {
            constexpr int mcb = 1 << kc;
#pragma unroll
            for (int r = 0; r < 4; ++r)
                if ((r & mcb) && !(r & mt)) { float2 t = a[r]; a[r] = a[r | mt]; a[r | mt] = t; }
        } else if constexpr (jc >= 0) {
            const bool p = (lane >> jc) & 1;
#pragma unroll
            for (int r = 0; r < 4; ++r)
                if (!(r & mt)) {
                    const float2 lo = a[r], hi = a[r | mt];
                    a[r].x = p ? hi.x : lo.x;       a[r].y = p ? hi.y : lo.y;
                    a[r | mt].x = p ? lo.x : hi.x;  a[r | mt].y = p ? lo.y : hi.y;
                }
        } else {
            if ((wv >> mc) & 1) {
#pragma unroll
                for (int r = 0; r < 4; ++r)
                    if (!(r & mt)) { float2 t = a[r]; a[r] = a[r | mt]; a[r | mt] = t; }
            }
        }
    } else {  // target on lane bit jt
        if constexpr (kc >= 0) {
            constexpr int mcb = 1 << kc;
#pragma unroll
            for (int r = 0; r < 4; ++r)
                if (r & mcb) { a[r].x = lx<jt>(a[r].x); a[r].y = lx<jt>(a[r].y); }
        } else if constexpr (jc >= 0) {
            const bool p = (lane >> jc) & 1;
#pragma unroll
            for (int r = 0; r < 4; ++r) {
                const float px = lx<jt>(a[r].x), py = lx<jt>(a[r].y);
                a[r].x = p ? px : a[r].x;  a[r].y = p ? py : a[r].y;
            }
        } else {
            if ((wv >> mc) & 1) {
#pragma unroll
                for (int r = 0; r < 4; ++r) { a[r].x = lx<jt>(a[r].x); a[r].y = lx<jt>(a[r].y); }
            }
        }
    }
}

// remap: write state with mapping PE (linear slots, swizzled), read with mapping CE
template <int PE, int CE>
__device__ __forceinline__ void remap(float2 (&a)[4], int lane, int wv, float2* st) {
    const int wbase = swzl((wv << 8) | (lane << 2));
#pragma unroll
    for (int r = 0; r < 4; ++r) st[wbase ^ r] = a[r];
    __syncthreads();
    const int rbase = swzl(slotOf(PE, stateOf(CE, wv, lane, 0)));
#pragma unroll
    for (int r = 0; r < 4; ++r) {
        const int d = swzl(slotOf(PE, stateOf(CE, 0, 0, r)));  // compile-time folds
        a[r] = st[rbase ^ d];
    }
    __syncthreads();
}

// ============ measurement masks: ring3 (CNOT(w,w+3)) absorbed, GF(2)-derived ============
constexpr int MASKW[12] = {0x124, 0x092, 0x049, 0x900, 0x480, 0x240,
                           0x920, 0x490, 0x248, 0x924, 0x492, 0x249};
constexpr int rmOf(int w) { int v = 0; for (int k = 0; k < 2; ++k) v |= ((MASKW[w] >> MP[3].rb[k]) & 1) << k; return v; }
constexpr int lmOf(int w) { int v = 0; for (int j = 0; j < 6; ++j) v |= ((MASKW[w] >> MP[3].lb[j]) & 1) << j; return v; }
constexpr int wmOf(int w) { int v = 0; for (int m = 0; m < 4; ++m) v |= ((MASKW[w] >> MP[3].wb[m]) & 1) << m; return v; }
constexpr int RMa[12] = {rmOf(0),rmOf(1),rmOf(2),rmOf(3),rmOf(4),rmOf(5),rmOf(6),rmOf(7),rmOf(8),rmOf(9),rmOf(10),rmOf(11)};
constexpr int LMa[12] = {lmOf(0),lmOf(1),lmOf(2),lmOf(3),lmOf(4),lmOf(5),lmOf(6),lmOf(7),lmOf(8),lmOf(9),lmOf(10),lmOf(11)};
constexpr int WMa[12] = {wmOf(0),wmOf(1),wmOf(2),wmOf(3),wmOf(4),wmOf(5),wmOf(6),wmOf(7),wmOf(8),wmOf(9),wmOf(10),wmOf(11)};

// ================= kernel 1: prep (projection + LN + gate build -> ws) =================
__global__ __launch_bounds__(256) void prep_gates(
    const float* __restrict__ x, const float* __restrict__ proj_w,
    const float* __restrict__ proj_b, const float* __restrict__ ln_w,
    const float* __restrict__ ln_b, const float* __restrict__ q_w,
    G4* __restrict__ wsF, G4* __restrict__ wsS) {
    __shared__ float hbuf[12];
    const int b = blockIdx.x;
    const int tid = threadIdx.x;
    const int lane = tid & 63;
    const int wv = tid >> 6;

    // projection h[j] = tanh(x[b].proj_w[j] + proj_b[j]) : wave wv -> outputs wv*3..+2
    {
        const float* xr = x + (size_t)b * D_IN;
        float xv[12];
#pragma unroll
        for (int k = 0; k < 12; ++k) xv[k] = xr[lane + k * 64];
#pragma unroll
        for (int jj = 0; jj < 3; ++jj) {
            const int j = wv * 3 + jj;
            const float* wr = proj_w + j * D_IN;
            float s = 0.f;
#pragma unroll
            for (int k = 0; k < 12; ++k) s += xv[k] * wr[lane + k * 64];
            s = waveRed(s);
            if (lane == 0) hbuf[j] = tanhf(s + proj_b[j]);
        }
    }
    __syncthreads();

    // gate build: tid = gate idx 0..35; 0..11 fused with LN+RY (per-batch), 12..35 shared (b==0 only)
    if (tid < 36 && (tid < 12 || b == 0)) {
        const float phi = q_w[3 * tid], th = q_w[3 * tid + 1], om = q_w[3 * tid + 2];
        float sth, cth, sa, ca, sb, cb;
        sincosf(0.5f * th, &sth, &cth);
        sincosf(0.5f * (phi + om), &sa, &ca);
        sincosf(0.5f * (phi - om), &sb, &cb);
        float R0r = cth * ca, R0i = -cth * sa;    // U00
        float R1r = -sth * cb, R1i = -sth * sb;   // U01
        float R2r = sth * cb, R2i = -sth * sb;    // U10
        float R3r = cth * ca, R3i = cth * sa;     // U11
        if (tid < 12) {
            float mu = 0.f;
#pragma unroll
            for (int k = 0; k < 12; ++k) mu += hbuf[k];
            mu *= (1.f / 12.f);
            float var = 0.f;
#pragma unroll
            for (int k = 0; k < 12; ++k) { const float d = hbuf[k] - mu; var += d * d; }
            var *= (1.f / 12.f);
            const float inv = 1.f / sqrtf(var + 1e-5f);
            const float ang = (hbuf[tid] - mu) * inv * ln_w[tid] + ln_b[tid];
            float sy, cy;
            sincosf(0.5f * ang, &sy, &cy);
            const float M0r = R0r * cy + R1r * sy, M0i = R0i * cy + R1i * sy;
            const float M1r = -R0r * sy + R1r * cy, M1i = -R0i * sy + R1i * cy;
            const float M2r = R2r * cy + R3r * sy, M2i = R2i * cy + R3i * sy;
            const float M3r = -R2r * sy + R3r * cy, M3i = -R2i * sy + R3i * cy;
            R0r = M0r; R0i = M0i; R1r = M1r; R1i = M1i;
            R2r = M2r; R2i = M2i; R3r = M3r; R3i = M3i;
        }
        G4 g;
        g.u00.rr = make_float2(R0r, R0r); g.u00.im = make_float2(-R0i, R0i);
        g.u01.rr = make_float2(R1r, R1r); g.u01.im = make_float2(-R1i, R1i);
        g.u10.rr = make_float2(R2r, R2r); g.u10.im = make_float2(-R2i, R2i);
        g.u11.rr = make_float2(R3r, R3r); g.u11.im = make_float2(-R3i, R3i);
        G4* dst = (tid < 12) ? (wsF + (size_t)b * 12 + tid) : (wsS + (tid - 12));
        *dst = g;
    }
}

// ================= kernel 2: circuit + measurement + MLP =================
__global__ __launch_bounds__(1024, 8) void hybrid_r7(
    const float* __restrict__ h1_w, const float* __restrict__ h1_b,
    const float* __restrict__ h2_w, const float* __restrict__ h2_b,
    const G4* __restrict__ wsF, const G4* __restrict__ wsS,
    float* __restrict__ out) {
    __shared__ float2 st[4096];   // 32 KB remap buffer
    __shared__ float red[12 * 16];
    __shared__ float z1[256];
    __shared__ float qz[12];

    const int b = blockIdx.x;
    const int tid = threadIdx.x;   // 0..1023
    const int lane = tid & 63;
    const int wv = tid >> 6;       // 0..15
    const G4* __restrict__ gF = wsF + (size_t)b * 12;

    // ---- state |0..0>: E0 maps i=0 -> wv0,lane0,r0 ----
    float2 a[4];
#pragma unroll
    for (int r = 0; r < 4; ++r) a[r] = make_float2(0.f, 0.f);
    if (tid == 0) a[0].x = 1.f;

    // ---- circuit ----
    // E0: reg={10,11} lane={4..9} wave={0,1,2,3}
    rotg<0, 11>(a, lane, gF + 0); rotg<0, 10>(a, lane, gF + 1); rotg<0, 9>(a, lane, gF + 2);
    rotg<0, 8>(a, lane, gF + 3);  rotg<0, 7>(a, lane, gF + 4);  rotg<0, 6>(a, lane, gF + 5);
    rotg<0, 5>(a, lane, gF + 6);  rotg<0, 4>(a, lane, gF + 7);
    cnot<0, 11, 10>(a, lane, wv); cnot<0, 10, 9>(a, lane, wv); cnot<0, 9, 8>(a, lane, wv);
    cnot<0, 8, 7>(a, lane, wv);   cnot<0, 7, 6>(a, lane, wv);  cnot<0, 6, 5>(a, lane, wv);
    cnot<0, 5, 4>(a, lane, wv);
    remap<0, 1>(a, lane, wv, st);
    // E1: reg={0,1} lane={2,3,8,9,10,11} wave={4,5,6,7}
    rotg<1, 3>(a, lane, gF + 8);  rotg<1, 2>(a, lane, gF + 9);
    rotg<1, 1>(a, lane, gF + 10); rotg<1, 0>(a, lane, gF + 11);
    cnot<1, 4, 3>(a, lane, wv); cnot<1, 3, 2>(a, lane, wv); cnot<1, 2, 1>(a, lane, wv);
    cnot<1, 1, 0>(a, lane, wv); cnot<1, 0, 11>(a, lane, wv);
    rotg<1, 11>(a, lane, wsS + 0); rotg<1, 10>(a, lane, wsS + 1);
    rotg<1, 9>(a, lane, wsS + 2);  rotg<1, 8>(a, lane, wsS + 3);
    rotg<1, 3>(a, lane, wsS + 8);  rotg<1, 2>(a, lane, wsS + 9);
    rotg<1, 1>(a, lane, wsS + 10); rotg<1, 0>(a, lane, wsS + 11);
    cnot<1, 11, 9>(a, lane, wv); cnot<1, 10, 8>(a, lane, wv);
    remap<1, 2>(a, lane, wv, st);
    // E2: reg={6,7} lane={5,4,2,3,0,1} wave={8,9,10,11}
    rotg<2, 7>(a, lane, wsS + 4); rotg<2, 6>(a, lane, wsS + 5);
    rotg<2, 5>(a, lane, wsS + 6); rotg<2, 4>(a, lane, wsS + 7);
    cnot<2, 9, 7>(a, lane, wv); cnot<2, 8, 6>(a, lane, wv); cnot<2, 7, 5>(a, lane, wv);
    cnot<2, 6, 4>(a, lane, wv); cnot<2, 5, 3>(a, lane, wv); cnot<2, 4, 2>(a, lane, wv);
    cnot<2, 3, 1>(a, lane, wv); cnot<2, 2, 0>(a, lane, wv);
    rotg<2, 7>(a, lane, wsS + 16); rotg<2, 6>(a, lane, wsS + 17);
    rotg<2, 5>(a, lane, wsS + 18); rotg<2, 4>(a, lane, wsS + 19);
    rotg<2, 3>(a, lane, wsS + 20); rotg<2, 2>(a, lane, wsS + 21);
    remap<2, 3>(a, lane, wv, st);
    // E3: reg={0,1} lane={2,3,8,9,10,11} wave={4,5,6,7}
    cnot<3, 1, 11>(a, lane, wv); cnot<3, 0, 10>(a, lane, wv);
    rotg<3, 11>(a, lane, wsS + 12); rotg<3, 10>(a, lane, wsS + 13);
    rotg<3, 9>(a, lane, wsS + 14);  rotg<3, 8>(a, lane, wsS + 15);
    rotg<3, 1>(a, lane, wsS + 22);  rotg<3, 0>(a, lane, wsS + 23);
    // ring3 absorbed into measurement masks.

    // ---- measurement ----
    {
        const float p0 = a[0].x * a[0].x + a[0].y * a[0].y;
        const float p1 = a[1].x * a[1].x + a[1].y * a[1].y;
        const float p2 = a[2].x * a[2].x + a[2].y * a[2].y;
        const float p3 = a[3].x * a[3].x + a[3].y * a[3].y;
        const float s[4] = {p0 + p1 + p2 + p3, p0 - p1 + p2 - p3,
                            p0 + p1 - p2 - p3, p0 - p1 - p2 + p3};
#pragma unroll
        for (int w = 0; w < 12; ++w) {
            const int sgn = (__popc(lane & LMa[w]) + __popc(wv & WMa[w])) & 1;
            float v = sgn ? -s[RMa[w]] : s[RMa[w]];
            v = waveRed(v);
            if (lane == 0) red[w * 16 + wv] = v;
        }
    }
    __syncthreads();
    if (tid < 12) {
        float q = 0.f;
#pragma unroll
        for (int m = 0; m < 16; ++m) q += red[tid * 16 + m];
        qz[tid] = q;
    }
    __syncthreads();

    // ---- MLP hidden: relu(q @ h1_w.T + h1_b) ----
    if (tid < 256) {
        float s = h1_b[tid];
#pragma unroll
        for (int k = 0; k < 12; ++k) s += qz[k] * h1_w[tid * 12 + k];
        z1[tid] = fmaxf(s, 0.f);
    }
    __syncthreads();

    // ---- out = z1 @ h2_w.T + h2_b : waves 0..13, 2 outputs each ----
    if (wv < 14) {
#pragma unroll
        for (int jj = 0; jj < 2; ++jj) {
            const int j = wv * 2 + jj;
            const float* wr = h2_w + j * 256;
            float s = 0.f;
#pragma unroll
            for (int k = 0; k < 4; ++k) s += z1[lane + k * 64] * wr[lane + k * 64];
            s = waveRed(s);
            if (lane == 0) out[(size_t)b * NLAB + j] = s + h2_b[j];
        }
    }
}

extern "C" void kernel_launch(void* const* d_in, const int* in_sizes, int n_in,
                              void* d_out, int out_size, void* d_ws, size_t ws_size,
                              hipStream_t stream) {
    const float* x      = (const float*)d_in[0];
    const float* proj_w = (const float*)d_in[1];
    const float* proj_b = (const float*)d_in[2];
    const float* ln_w   = (const float*)d_in[3];
    const float* ln_b   = (const float*)d_in[4];
    const float* q_w    = (const float*)d_in[5];
    const float* h1_w   = (const float*)d_in[6];
    const float* h1_b   = (const float*)d_in[7];
    const float* h2_w   = (const float*)d_in[8];
    const float* h2_b   = (const float*)d_in[9];
    float* out = (float*)d_out;

    const int B = in_sizes[0] / D_IN;  // 512
    G4* wsF = (G4*)d_ws;               // B*12 fused L0 gates
    G4* wsS = wsF + (size_t)B * 12;    // 24 shared L1/L2 gates

    prep_gates<<<dim3(B), dim3(256), 0, stream>>>(x, proj_w, proj_b, ln_w, ln_b,
                                                  q_w, wsF, wsS);
    hybrid_r7<<<dim3(B), dim3(1024), 0, stream>>>(h1_w, h1_b, h2_w, h2_b,
                                                  wsF, wsS, out);
}